// Round 7
// baseline (281.587 us; speedup 1.0000x reference)
//
#include <hip/hip_runtime.h>

typedef __bf16 bf16x8 __attribute__((ext_vector_type(8)));
typedef float f32x4 __attribute__((ext_vector_type(4)));
typedef unsigned int u32;

#define ROW_B   304                 // bytes per row within one copy (152 elems)
#define COPY_B  (31 * ROW_B)        // 9424 B per copy
#define NCOPY   4                   // copies shifted by 0,1,2,3 elements

__device__ __forceinline__ unsigned short f2bf(float f) {
    u32 u = __builtin_bit_cast(u32, f);
    return (unsigned short)((u + 0x7FFFu + ((u >> 16) & 1u)) >> 16);  // RNE
}
__device__ __forceinline__ int refl(int i) {  // reflect index into [0,512)
    return i < 0 ? -i : (i > 511 ? 1022 - i : i);
}

// Block (x=half, y=h0/16, z=n): sample n, rows h0..h0+15, cols [256*half,+256)
// as 2 chunks of 128. Wave w owns cols [16w,16w+16) of each 64-col subtile.
// K = 15x15 taps padded to 16x16 = 256 = 8 MFMA K-steps (HW-validated mapping):
// k = 32*ks + 8*g + j  ->  kh = 2*ks + (g>>1), kw = 8*(g&1) + j   (g = lane>>4)
// B-fragment for (ks,t): 8 bf16 at staged elem X..X+7, X = w0*64+wave*16+g1*8+t+1.
// Copy c = X mod 4 holds elem e at byte 2(e-c) -> every fragment is a direct
// aligned LDS read at an immediate offset. Zero VALU in the inner loop.
template <int MODE>
__global__ __launch_bounds__(256, 4) void dynconv(const float* __restrict__ x,
                                                  const float* __restrict__ kern,
                                                  float* __restrict__ out,
                                                  float* __restrict__ partial) {
    __shared__ __align__(16) unsigned short lds4[NCOPY * COPY_B / 2];  // 37696 B
    __shared__ float wm[4];

    const int tid  = threadIdx.x;
    const int lane = tid & 63;
    const int wave = tid >> 6;
    const int half = blockIdx.x;            // 0/1: which 256-col half
    const int h0   = blockIdx.y * 16;
    const int n    = blockIdx.z;
    const int hbase = half * 256;

    const float* xs = x + (size_t)n * (16u * 512u * 512u);

    // ---- A fragments: kernel weights, zero-padded to 16x16 taps ----
    const int oca = lane & 15;
    const int g   = lane >> 4;
    const int g1  = g & 1;
    const int g2  = g >> 1;
    bf16x8 afrag[8];
    {
        const float* kp = kern + ((size_t)n * 16 + oca) * 225;
        #pragma unroll
        for (int ks = 0; ks < 8; ++ks) {
            const int kh = 2 * ks + g2;
            #pragma unroll
            for (int j = 0; j < 8; ++j) {
                const int kwv = 8 * g1 + j;
                float v = 0.f;
                if (kh < 15 && kwv < 15) v = kp[kh * 15 + kwv];
                afrag[ks][j] = (__bf16)v;
            }
        }
    }

    // ---- MODE 1: per-sample max from the 64 partials of sample n ----
    float scale = 0.f;
    if constexpr (MODE == 1) {
        float pv = partial[(n << 6) + lane];
        #pragma unroll
        for (int off = 32; off > 0; off >>= 1) pv = fmaxf(pv, __shfl_xor(pv, off, 64));
        scale = 1.0f / pv;
    }

    const int hh = lane & 15;               // B n-dim: output row offset

    // ---- stage 4 shifted copies of a 31 x 144 tile (cols c0q-8..c0q+135) ----
    // unit (rr, cs): elems 8cs..8cs+10 of row rr; copy c gets elems 8cs+c..+7.
    auto stage = [&](int c0q) {
        for (int u = tid; u < 31 * 18; u += 256) {
            const int rr = u / 18;
            const int cs = u - rr * 18;
            const float* rowp = xs + refl(h0 - 7 + rr) * 512;
            const int gc0 = c0q - 8 + 8 * cs;
            float v[11];
            if (gc0 >= 0 && gc0 <= 501) {           // interior fast path
                const float4 a  = *(const float4*)(rowp + gc0);
                const float4 b4 = *(const float4*)(rowp + gc0 + 4);
                v[0] = a.x;  v[1] = a.y;  v[2] = a.z;  v[3] = a.w;
                v[4] = b4.x; v[5] = b4.y; v[6] = b4.z; v[7] = b4.w;
                v[8] = rowp[gc0 + 8]; v[9] = rowp[gc0 + 9]; v[10] = rowp[gc0 + 10];
            } else {                                // border reflect, scalar
                #pragma unroll
                for (int i = 0; i < 11; ++i) v[i] = rowp[refl(gc0 + i)];
            }
            unsigned short b[11];
            #pragma unroll
            for (int i = 0; i < 11; ++i) b[i] = f2bf(v[i]);
            char* wp = (char*)lds4 + rr * ROW_B + 16 * cs;
            #pragma unroll
            for (int c = 0; c < NCOPY; ++c) {
                uint4 q;
                q.x = (u32)b[c]     | ((u32)b[c + 1] << 16);
                q.y = (u32)b[c + 2] | ((u32)b[c + 3] << 16);
                q.z = (u32)b[c + 4] | ((u32)b[c + 5] << 16);
                q.w = (u32)b[c + 6] | ((u32)b[c + 7] << 16);
                *(uint4*)(wp + c * COPY_B) = q;
            }
        }
    };

    // per-lane LDS base: row (hh+g2), col words for (wave,g1); rest is immediate
    const char* lbase = (const char*)lds4 + (hh + g2) * ROW_B + 32 * wave + 16 * g1;

    // ---- conv of one 16h x 64w subtile (w0 compile-time) ----
    auto conv = [&](auto w0c, f32x4* acc) {
        constexpr int w0 = decltype(w0c)::value;
        #pragma unroll
        for (int t = 0; t < 16; ++t) acc[t] = f32x4{0.f, 0.f, 0.f, 0.f};
        #pragma unroll
        for (int ks = 0; ks < 8; ++ks) {
            #pragma unroll
            for (int t = 0; t < 16; ++t) {
                const int c   = (t + 1) & 3;
                const int sh  = (t + 1) - c;          // multiple of 4
                const int off = c * COPY_B + ks * (2 * ROW_B) + w0 * 128 + 2 * sh;
                uint4 dv;
                if ((sh & 4) == 0) {                  // 16B-aligned: one b128
                    dv = *(const uint4*)(lbase + off);
                } else {                              // 8B-aligned: two b64
                    const uint2 lo = *(const uint2*)(lbase + off);
                    const uint2 hi = *(const uint2*)(lbase + off + 8);
                    dv.x = lo.x; dv.y = lo.y; dv.z = hi.x; dv.w = hi.y;
                }
                acc[t] = __builtin_amdgcn_mfma_f32_16x16x32_bf16(
                    afrag[ks], __builtin_bit_cast(bf16x8, dv), acc[t], 0, 0, 0);
            }
        }
    };

    float m = -3.4e38f;
    #pragma unroll 1
    for (int ch = 0; ch < 2; ++ch) {
        __syncthreads();
        stage(hbase + ch * 128);
        __syncthreads();
        #pragma unroll
        for (int w0 = 0; w0 < 2; ++w0) {
            f32x4 acc[16];
            if (w0 == 0) conv(std::integral_constant<int, 0>{}, acc);
            else         conv(std::integral_constant<int, 1>{}, acc);
            if constexpr (MODE == 0) {
                #pragma unroll
                for (int t = 0; t < 16; ++t)
                    #pragma unroll
                    for (int r = 0; r < 4; ++r) m = fmaxf(m, acc[t][r]);
            } else {
                // direct stores: lane covers w = wave*16 + 4q..4q+3 (64B/lane line)
                #pragma unroll
                for (int r = 0; r < 4; ++r) {
                    const int oc = 4 * g + r;
                    float* rowp = out + (((size_t)(oc * 16 + n)) * 512 + (h0 + hh)) * 512
                                  + hbase + ch * 128 + w0 * 64 + wave * 16;
                    #pragma unroll
                    for (int q = 0; q < 4; ++q) {
                        f32x4 v;
                        v[0] = acc[4 * q + 0][r] * scale;
                        v[1] = acc[4 * q + 1][r] * scale;
                        v[2] = acc[4 * q + 2][r] * scale;
                        v[3] = acc[4 * q + 3][r] * scale;
                        *(f32x4*)(rowp + 4 * q) = v;
                    }
                }
            }
        }
    }

    if constexpr (MODE == 0) {
        #pragma unroll
        for (int off = 32; off > 0; off >>= 1) m = fmaxf(m, __shfl_xor(m, off, 64));
        if (lane == 0) wm[wave] = m;
        __syncthreads();
        if (tid == 0)
            partial[((blockIdx.z * 32 + blockIdx.y) << 1) + blockIdx.x] =
                fmaxf(fmaxf(wm[0], wm[1]), fmaxf(wm[2], wm[3]));
    }
}

extern "C" void kernel_launch(void* const* d_in, const int* in_sizes, int n_in,
                              void* d_out, int out_size, void* d_ws, size_t ws_size,
                              hipStream_t stream) {
    (void)in_sizes; (void)n_in; (void)out_size; (void)ws_size;
    const float* x  = (const float*)d_in[0];
    const float* k  = (const float*)d_in[1];
    float* out      = (float*)d_out;
    float* partial  = (float*)d_ws;          // 1024 floats

    dim3 grid(2, 32, 16);   // (col half, h-tile, sample) = 1024 blocks = 4/CU
    dim3 block(256);
    dynconv<0><<<grid, block, 0, stream>>>(x, k, out, partial);  // max pass
    dynconv<1><<<grid, block, 0, stream>>>(x, k, out, partial);  // scale+store pass
}